// Round 1
// baseline (1525.069 us; speedup 1.0000x reference)
//
#include <hip/hip_runtime.h>
#include <math.h>

#define T_ 8
#define NNODES 100000
#define F_ 128
#define B_ 4096
#define S1_ 5
#define S2_ 2
#define H1_ 512
#define H2_ 64
#define O_ 32
#define M1 (B_ + B_*S1_)      /* 24576 rows: [h0-block | h1-block] */
#define K1 (2*F_)             /* 256: [h | agg] */
#define NZ 12                 /* (t,c) pairs: z<8 -> (z,0); z>=8 -> (2*(z-8),1) */

__device__ __forceinline__ float wsum64(float v) {
#pragma unroll
  for (int o = 32; o > 0; o >>= 1) v += __shfl_xor(v, o, 64);
  return v;
}

// ---------------------------------------------------------------- pos table
// matches np: angle computed in fp64, sin/cos fp64, cast to fp32
__global__ __launch_bounds__(512) void postab_kernel(float* __restrict__ postab) {
  int i = threadIdx.x;            // 0..511
  int p = i >> 6, d = i & 63;
  double ang = (double)p / pow(10000.0, (2.0 * (double)(d >> 1)) / 64.0);
  postab[i] = (float)((d & 1) ? cos(ang) : sin(ang));
}

// ---------------------------------------------------------------- gather+agg
// A[t] : [M1][K1] f32.  rows 0..B-1: [x[t,nodes[b]] | mean_S1 x[t,hop1]]
//                       rows B..   : [x[t,hop1[j]]  | mean_S2 x[t,hop2]]
// one wave per row: lanes 0..31 = h part (float4 each), 32..63 = agg part
__global__ __launch_bounds__(256) void gather_kernel(
    const int* __restrict__ nodes, const int* __restrict__ hop1,
    const int* __restrict__ hop2, const float* __restrict__ x,
    float* __restrict__ Abase)
{
  const int t = blockIdx.y;
  const int r = blockIdx.x * 4 + (threadIdx.x >> 6);
  const int lane = threadIdx.x & 63;
  const int fo = (lane & 31) << 2;          // float offset within 128
  const bool hpart = lane < 32;
  const float* xt = x + (size_t)t * NNODES * F_;
  float4 v;
  if (r < B_) {
    if (hpart) {
      int node = nodes[r];
      v = *(const float4*)(xt + (size_t)node * F_ + fo);
    } else {
      v = make_float4(0.f, 0.f, 0.f, 0.f);
#pragma unroll
      for (int s = 0; s < S1_; ++s) {
        int idx = hop1[t * (B_ * S1_) + r * S1_ + s];
        float4 u = *(const float4*)(xt + (size_t)idx * F_ + fo);
        v.x += u.x; v.y += u.y; v.z += u.z; v.w += u.w;
      }
      v.x /= 5.0f; v.y /= 5.0f; v.z /= 5.0f; v.w /= 5.0f;  // match np div
    }
  } else {
    const int j = r - B_;
    if (hpart) {
      int idx = hop1[t * (B_ * S1_) + j];
      v = *(const float4*)(xt + (size_t)idx * F_ + fo);
    } else {
      v = make_float4(0.f, 0.f, 0.f, 0.f);
#pragma unroll
      for (int s = 0; s < S2_; ++s) {
        int idx = hop2[t * (B_ * S1_ * S2_) + j * S2_ + s];
        float4 u = *(const float4*)(xt + (size_t)idx * F_ + fo);
        v.x += u.x; v.y += u.y; v.z += u.z; v.w += u.w;
      }
      v.x *= 0.5f; v.y *= 0.5f; v.z *= 0.5f; v.w *= 0.5f;  // /2 exact
    }
  }
  float* Arow = Abase + ((size_t)t * M1 + r) * K1;
  *(float4*)(Arow + 4 * lane) = v;   // lane<32 -> h part; lane>=32 -> 128+.. (4*lane works for both)
}

// ---------------------------------------------------------------- GEMM1 + spike
// S[z] = spike(A[t] @ [Ws1[c];Wn1[c]]) as uint8.  M=24576 N=512 K=256 fp32.
// 128x128 tile, 256 thr, 8x8/thread, BK=16, double-buffered LDS.
__global__ __launch_bounds__(256)
void gemm1_kernel(const float* __restrict__ Abase,
                  const float* __restrict__ Wself1,
                  const float* __restrict__ Wnbr1,
                  unsigned char* __restrict__ Sbase)
{
  const int z = blockIdx.z;
  const int t = (z < 8) ? z : 2 * (z - 8);
  const int c = (z < 8) ? 0 : 1;
  const float* __restrict__ A   = Abase + (size_t)t * M1 * K1;
  const float* __restrict__ Bw0 = Wself1 + (size_t)c * F_ * H1_;
  const float* __restrict__ Bw1 = Wnbr1  + (size_t)c * F_ * H1_;
  unsigned char* __restrict__ S = Sbase + (size_t)z * M1 * H1_;

  const int m0 = blockIdx.y * 128;
  const int n0 = blockIdx.x * 128;
  const int tid = threadIdx.x;

  __shared__ float As[2][16][132];   // [k][m], padded
  __shared__ float Bs[2][16][132];   // [k][n], padded

  const int arow = tid >> 2;            // 0..63
  const int acol = (tid & 3) << 2;      // 0,4,8,12
  const int brow = tid >> 5;            // 0..7
  const int bcol = (tid & 31) << 2;     // 0..124
  const int ty = tid >> 4;              // 0..15 (rows)
  const int tx = tid & 15;              // 0..15 (cols, split-64 halves)

  float acc[8][8];
#pragma unroll
  for (int i = 0; i < 8; ++i)
#pragma unroll
    for (int j = 0; j < 8; ++j) acc[i][j] = 0.f;

  float4 pa0, pa1, pb0, pb1;

  auto loadTile = [&](int kt) {
    const int k0 = kt * 16;
    pa0 = *(const float4*)(A + (size_t)(m0 + arow) * K1 + k0 + acol);
    pa1 = *(const float4*)(A + (size_t)(m0 + arow + 64) * K1 + k0 + acol);
    const int kg0 = k0 + brow;
    const int kg1 = kg0 + 8;
    const float* p0 = (kg0 < F_) ? (Bw0 + (size_t)kg0 * H1_) : (Bw1 + (size_t)(kg0 - F_) * H1_);
    const float* p1 = (kg1 < F_) ? (Bw0 + (size_t)kg1 * H1_) : (Bw1 + (size_t)(kg1 - F_) * H1_);
    pb0 = *(const float4*)(p0 + n0 + bcol);
    pb1 = *(const float4*)(p1 + n0 + bcol);
  };
  auto storeTile = [&](int buf) {
    As[buf][acol + 0][arow] = pa0.x;
    As[buf][acol + 1][arow] = pa0.y;
    As[buf][acol + 2][arow] = pa0.z;
    As[buf][acol + 3][arow] = pa0.w;
    As[buf][acol + 0][arow + 64] = pa1.x;
    As[buf][acol + 1][arow + 64] = pa1.y;
    As[buf][acol + 2][arow + 64] = pa1.z;
    As[buf][acol + 3][arow + 64] = pa1.w;
    *(float4*)&Bs[buf][brow][bcol]     = pb0;
    *(float4*)&Bs[buf][brow + 8][bcol] = pb1;
  };

  loadTile(0);
  storeTile(0);
  __syncthreads();

#pragma unroll 1
  for (int kt = 0; kt < 16; ++kt) {
    const int cur = kt & 1;
    if (kt < 15) loadTile(kt + 1);
#pragma unroll
    for (int kk = 0; kk < 16; ++kk) {
      float4 t0 = *(const float4*)&As[cur][kk][ty * 8];
      float4 t1 = *(const float4*)&As[cur][kk][ty * 8 + 4];
      float4 t2 = *(const float4*)&Bs[cur][kk][tx * 4];        // cols [tx*4 .. +3]
      float4 t3 = *(const float4*)&Bs[cur][kk][64 + tx * 4];   // cols [64+tx*4 .. +3]
      float a[8] = {t0.x, t0.y, t0.z, t0.w, t1.x, t1.y, t1.z, t1.w};
      float b[8] = {t2.x, t2.y, t2.z, t2.w, t3.x, t3.y, t3.z, t3.w};
#pragma unroll
      for (int i = 0; i < 8; ++i)
#pragma unroll
        for (int j = 0; j < 8; ++j) acc[i][j] += a[i] * b[j];
    }
    if (kt < 15) {
      storeTile(cur ^ 1);
      __syncthreads();
    }
  }

  // spike + uint8 store (two 4-byte packs per row: col halves tx*4 and 64+tx*4)
#pragma unroll
  for (int i = 0; i < 8; ++i) {
    unsigned int lo = 0, hi = 0;
#pragma unroll
    for (int j = 0; j < 4; ++j) {
      if (acc[i][j]     >= 1.0f) lo |= (1u << (8 * j));
      if (acc[i][4 + j] >= 1.0f) hi |= (1u << (8 * j));
    }
    unsigned char* row = S + (size_t)(m0 + ty * 8 + i) * H1_ + n0;
    *(unsigned int*)(row + tx * 4)      = lo;
    *(unsigned int*)(row + 64 + tx * 4) = hi;
  }
}

// ---------------------------------------------------------------- GEMM2 + spike
// outs[z] = spike([s0 | mean_S1 s1] @ [Ws2[c];Wn2[c]]).  M=4096 N=64 K=1024.
// A built on the fly from binary S (group-sum exact int; q*0.2f == fl(q/5)).
__global__ __launch_bounds__(256)
void gemm2_kernel(const unsigned char* __restrict__ Sbase,
                  const float* __restrict__ Wself2,
                  const float* __restrict__ Wnbr2,
                  unsigned char* __restrict__ outsbase)
{
  const int z = blockIdx.y;
  const int c = (z < 8) ? 0 : 1;
  const unsigned char* __restrict__ S = Sbase + (size_t)z * M1 * H1_;
  const float* __restrict__ Bw0 = Wself2 + (size_t)c * H1_ * H2_;
  const float* __restrict__ Bw1 = Wnbr2  + (size_t)c * H1_ * H2_;
  unsigned char* __restrict__ outs = outsbase + (size_t)z * B_ * H2_;
  const int m0 = blockIdx.x * 64;
  const int tid = threadIdx.x;

  __shared__ float As2[32][68];
  __shared__ float Bs2[32][68];

  const int arow = tid >> 2;        // 0..63 (m)
  const int acol = (tid & 3) << 3;  // 0,8,16,24 (k in tile, 8 each)
  const int brow = tid >> 4;        // 0..15
  const int bcol = (tid & 15) << 2; // 0..60
  const int ty = tid >> 4;          // 0..15
  const int tx = tid & 15;          // 0..15

  float acc[4][4];
#pragma unroll
  for (int i = 0; i < 4; ++i)
#pragma unroll
    for (int j = 0; j < 4; ++j) acc[i][j] = 0.f;

#pragma unroll 1
  for (int kt = 0; kt < 32; ++kt) {
    const int k0 = kt * 32;
    float av[8];
    if (k0 < H1_) {  // s0 part: binary
      const unsigned char* p = S + (size_t)(m0 + arow) * H1_ + k0 + acol;
      unsigned long long u = *(const unsigned long long*)p;
#pragma unroll
      for (int e = 0; e < 8; ++e) av[e] = (float)((u >> (8 * e)) & 0xFFull);
    } else {         // agg part: sum of 5 binary rows, * 0.2f
      const int kk0 = k0 - H1_ + acol;
      unsigned int q[8] = {0, 0, 0, 0, 0, 0, 0, 0};
#pragma unroll
      for (int s = 0; s < S1_; ++s) {
        const unsigned char* p =
            S + ((size_t)B_ + (size_t)(m0 + arow) * S1_ + s) * H1_ + kk0;
        unsigned long long u = *(const unsigned long long*)p;
#pragma unroll
        for (int e = 0; e < 8; ++e) q[e] += (unsigned)((u >> (8 * e)) & 0xFFull);
      }
#pragma unroll
      for (int e = 0; e < 8; ++e) av[e] = (float)q[e] * 0.2f;
    }
    const int kg0 = k0 + brow, kg1 = kg0 + 16;
    const float* p0 = (kg0 < H1_) ? (Bw0 + (size_t)kg0 * H2_) : (Bw1 + (size_t)(kg0 - H1_) * H2_);
    const float* p1 = (kg1 < H1_) ? (Bw0 + (size_t)kg1 * H2_) : (Bw1 + (size_t)(kg1 - H1_) * H2_);
    float4 pb0 = *(const float4*)(p0 + bcol);
    float4 pb1 = *(const float4*)(p1 + bcol);

    __syncthreads();
#pragma unroll
    for (int e = 0; e < 8; ++e) As2[acol + e][arow] = av[e];
    *(float4*)&Bs2[brow][bcol]      = pb0;
    *(float4*)&Bs2[brow + 16][bcol] = pb1;
    __syncthreads();

#pragma unroll
    for (int kk = 0; kk < 32; ++kk) {
      float4 a4 = *(const float4*)&As2[kk][ty * 4];
      float4 b4 = *(const float4*)&Bs2[kk][tx * 4];
      float a[4] = {a4.x, a4.y, a4.z, a4.w};
      float b[4] = {b4.x, b4.y, b4.z, b4.w};
#pragma unroll
      for (int i = 0; i < 4; ++i)
#pragma unroll
        for (int j = 0; j < 4; ++j) acc[i][j] += a[i] * b[j];
    }
  }
#pragma unroll
  for (int i = 0; i < 4; ++i) {
    unsigned int pack = 0;
#pragma unroll
    for (int j = 0; j < 4; ++j)
      if (acc[i][j] >= 1.0f) pack |= (1u << (8 * j));
    *(unsigned int*)(outs + (size_t)(m0 + ty * 4 + i) * H2_ + tx * 4) = pack;
  }
}

// ---------------------------------------------------------------- attention + head
// one wave per b; lane = h (H2 == 64 == wave width)
__global__ __launch_bounds__(256)
void final_kernel(const unsigned char* __restrict__ outsbase,
                  const float* __restrict__ postab,
                  const float* __restrict__ apw, const float* __restrict__ apb,
                  const float* __restrict__ anw, const float* __restrict__ anb,
                  const float* __restrict__ mtgw, const float* __restrict__ mtgb,
                  float* __restrict__ out)
{
  const int b = blockIdx.x * 4 + (threadIdx.x >> 6);
  const int lane = threadIdx.x & 63;
  float stacked = 0.f;
#pragma unroll
  for (int c = 0; c < 2; ++c) {
    const int Tc = c ? 4 : 8;
    const int zb = c ? 8 : 0;
    const float wp = apw[c * H2_ + lane];
    const float wn = anw[c * H2_ + lane];
    float seqv[8], sp[8], sn[8];
#pragma unroll
    for (int tt = 0; tt < Tc; ++tt) {
      const float sv = (float)outsbase[((size_t)(zb + tt) * B_ + b) * H2_ + lane];
      seqv[tt] = sv;
      const float pv = sv + postab[tt * H2_ + lane];
      sp[tt] = wsum64(pv * wp);
      sn[tt] = wsum64(sv * wn);
    }
    const float bp = apb[c], bn = anb[c];
    float mp = -3.4e38f, mn = -3.4e38f;
#pragma unroll
    for (int tt = 0; tt < Tc; ++tt) {
      sp[tt] += bp; sn[tt] += bn;
      mp = fmaxf(mp, sp[tt]); mn = fmaxf(mn, sn[tt]);
    }
    float ep[8], en[8], sump = 0.f, sumn = 0.f;
#pragma unroll
    for (int tt = 0; tt < Tc; ++tt) {
      ep[tt] = __expf(sp[tt] - mp) * 0.f + expf(sp[tt] - mp);  // use precise expf
      en[tt] = expf(sn[tt] - mn);
      sump += ep[tt]; sumn += en[tt];
    }
    float embp = 0.f, embn = 0.f;
#pragma unroll
    for (int tt = 0; tt < Tc; ++tt) {
      embp += (seqv[tt] + postab[tt * H2_ + lane]) * (ep[tt] / sump);
      embn += seqv[tt] * (en[tt] / sumn);
    }
    stacked += 0.5f * (0.6f * embp + 0.4f * embn);
  }
  float res = 0.f;
#pragma unroll
  for (int o = 0; o < O_; ++o) {
    float r = wsum64(stacked * mtgw[lane * O_ + o]);
    if (lane == o) res = r;
  }
  if (lane < O_) out[(size_t)b * O_ + lane] = res + mtgb[lane];
}

// ---------------------------------------------------------------- launch
extern "C" void kernel_launch(void* const* d_in, const int* in_sizes, int n_in,
                              void* d_out, int out_size, void* d_ws, size_t ws_size,
                              hipStream_t stream)
{
  const int*   nodes  = (const int*)d_in[0];
  const int*   hop1   = (const int*)d_in[1];
  const int*   hop2   = (const int*)d_in[2];
  const float* x      = (const float*)d_in[3];
  const float* Wself1 = (const float*)d_in[4];
  const float* Wnbr1  = (const float*)d_in[5];
  const float* Wself2 = (const float*)d_in[6];
  const float* Wnbr2  = (const float*)d_in[7];
  const float* apw    = (const float*)d_in[8];
  const float* apb    = (const float*)d_in[9];
  const float* anw    = (const float*)d_in[10];
  const float* anb    = (const float*)d_in[11];
  const float* mtgw   = (const float*)d_in[12];
  const float* mtgb   = (const float*)d_in[13];
  float* out = (float*)d_out;

  char* ws = (char*)d_ws;
  size_t off = 0;
  float* postab = (float*)(ws + off);          off += 4096;
  float* Abase  = (float*)(ws + off);          off += (size_t)T_ * M1 * K1 * 4;   // 201.3 MB
  unsigned char* Sbase = (unsigned char*)(ws + off); off += (size_t)NZ * M1 * H1_; // 151.0 MB
  unsigned char* outsb = (unsigned char*)(ws + off); off += (size_t)NZ * B_ * H2_; //   3.1 MB
  if (ws_size < off) return;  // insufficient scratch -> loud correctness failure

  hipLaunchKernelGGL(postab_kernel, dim3(1), dim3(512), 0, stream, postab);
  hipLaunchKernelGGL(gather_kernel, dim3(M1 / 4, T_), dim3(256), 0, stream,
                     nodes, hop1, hop2, x, Abase);
  hipLaunchKernelGGL(gemm1_kernel, dim3(4, M1 / 128, NZ), dim3(256), 0, stream,
                     Abase, Wself1, Wnbr1, Sbase);
  hipLaunchKernelGGL(gemm2_kernel, dim3(B_ / 64, NZ), dim3(256), 0, stream,
                     Sbase, Wself2, Wnbr2, outsb);
  hipLaunchKernelGGL(final_kernel, dim3(B_ / 4), dim3(256), 0, stream,
                     outsb, postab, apw, apb, anw, anb, mtgw, mtgb, out);
}

// Round 2
// 900.561 us; speedup vs baseline: 1.6935x; 1.6935x over previous
//
#include <hip/hip_runtime.h>
#include <math.h>

typedef _Float16 f16;
typedef _Float16 f16x8 __attribute__((ext_vector_type(8)));
typedef float f32x4 __attribute__((ext_vector_type(4)));

#define T_ 8
#define NNODES 100000
#define F_ 128
#define B_ 4096
#define S1_ 5
#define S2_ 2
#define H1_ 512
#define H2_ 64
#define O_ 32
#define M1 (B_ + B_*S1_)      /* 24576 rows: [h0-block | h1-block] */
#define K1 (2*F_)             /* 256: [h | agg] */
#define NZ 12                 /* z<8 -> (t=z,c=0); z>=8 -> (t=2*(z-8),c=1) */

__device__ __forceinline__ float wsum64(float v) {
#pragma unroll
  for (int o = 32; o > 0; o >>= 1) v += __shfl_xor(v, o, 64);
  return v;
}

// ---------------------------------------------------------------- pos table
__global__ __launch_bounds__(512) void postab_kernel(float* __restrict__ postab) {
  int i = threadIdx.x;
  int p = i >> 6, d = i & 63;
  double ang = (double)p / pow(10000.0, (2.0 * (double)(d >> 1)) / 64.0);
  postab[i] = (float)((d & 1) ? cos(ang) : sin(ang));
}

// ---------------------------------------------------------------- weight limbs
// Bt[c][n=512][k=256] f16, k<128 from Wself1, k>=128 from Wnbr1 (transposed)
__global__ __launch_bounds__(256)
void prep_w(const float* __restrict__ Ws1, const float* __restrict__ Wn1,
            f16* __restrict__ Bth, f16* __restrict__ Btl) {
  const int bid = blockIdx.x;            // 0..1023
  const int c = bid >> 9, n = bid & 511;
  const int k = threadIdx.x;             // 0..255
  float wv = (k < F_) ? Ws1[((size_t)c * F_ + k) * H1_ + n]
                      : Wn1[((size_t)c * F_ + (k - F_)) * H1_ + n];
  f16 hi = (f16)wv;
  f16 lo = (f16)((wv - (float)hi) * 2048.0f);   // exact split; lo pre-scaled 2^11
  size_t o = ((size_t)c * H1_ + n) * K1 + k;
  Bth[o] = hi; Btl[o] = lo;
}

// ---------------------------------------------------------------- gather+agg
// Ah/Al[t][M1][256] f16 limbs of [h | agg]; one wave per row.
__global__ __launch_bounds__(256) void gather_kernel(
    const int* __restrict__ nodes, const int* __restrict__ hop1,
    const int* __restrict__ hop2, const float* __restrict__ x,
    f16* __restrict__ Ah, f16* __restrict__ Al)
{
  const int t = blockIdx.y;
  const int r = blockIdx.x * 4 + (threadIdx.x >> 6);
  const int lane = threadIdx.x & 63;
  const int fo = (lane & 31) << 2;
  const bool hpart = lane < 32;
  const float* xt = x + (size_t)t * NNODES * F_;
  float4 v;
  if (r < B_) {
    if (hpart) {
      v = *(const float4*)(xt + (size_t)nodes[r] * F_ + fo);
    } else {
      v = make_float4(0.f, 0.f, 0.f, 0.f);
#pragma unroll
      for (int s = 0; s < S1_; ++s) {
        int idx = hop1[t * (B_ * S1_) + r * S1_ + s];
        float4 u = *(const float4*)(xt + (size_t)idx * F_ + fo);
        v.x += u.x; v.y += u.y; v.z += u.z; v.w += u.w;
      }
      v.x /= 5.0f; v.y /= 5.0f; v.z /= 5.0f; v.w /= 5.0f;
    }
  } else {
    const int j = r - B_;
    if (hpart) {
      v = *(const float4*)(xt + (size_t)hop1[t * (B_ * S1_) + j] * F_ + fo);
    } else {
      v = make_float4(0.f, 0.f, 0.f, 0.f);
#pragma unroll
      for (int s = 0; s < S2_; ++s) {
        int idx = hop2[t * (B_ * S1_ * S2_) + j * S2_ + s];
        float4 u = *(const float4*)(xt + (size_t)idx * F_ + fo);
        v.x += u.x; v.y += u.y; v.z += u.z; v.w += u.w;
      }
      v.x *= 0.5f; v.y *= 0.5f; v.z *= 0.5f; v.w *= 0.5f;
    }
  }
  union { f16 h[4]; uint2 u; } H, L;
  float vv[4] = {v.x, v.y, v.z, v.w};
#pragma unroll
  for (int e = 0; e < 4; ++e) {
    f16 hi = (f16)vv[e];
    H.h[e] = hi;
    L.h[e] = (f16)((vv[e] - (float)hi) * 2048.0f);
  }
  const size_t base = ((size_t)t * M1 + r) * K1 + 4 * lane;
  *(uint2*)(Ah + base) = H.u;
  *(uint2*)(Al + base) = L.u;
}

// ---------------------------------------------------------------- GEMM1 (MFMA fp16x3) + spike
// S[z] = spike(A[t] @ B[c]); M=24576 N=512 K=256. 128x128 tile, 4 waves,
// 64x64/wave, BK=32. LDS [tile][k8][row][8] fragment-ready; global_load_lds 16B.
__global__ __launch_bounds__(256)
void gemm1_mfma(const f16* __restrict__ Ah, const f16* __restrict__ Al,
                const f16* __restrict__ Bth, const f16* __restrict__ Btl,
                unsigned char* __restrict__ Sbase)
{
  const int z = blockIdx.z;
  const int t = (z < 8) ? z : 2 * (z - 8);
  const int c = (z < 8) ? 0 : 1;
  const int m0 = blockIdx.y * 128;
  const int n0 = blockIdx.x * 128;
  const int tid = threadIdx.x;
  const int lane = tid & 63;
  const int w = tid >> 6;
  const int wr = w >> 1, wc = w & 1;      // wave tile (wr*64, wc*64)

  __shared__ f16 lds[4][4][128][8];       // [tile 0:Ah 1:Al 2:Bh 3:Bl][k8][row][8] = 32KB

  const f16* tb0 = Ah  + (size_t)t * M1 * K1;
  const f16* tb1 = Al  + (size_t)t * M1 * K1;
  const f16* tb2 = Bth + (size_t)c * H1_ * K1;
  const f16* tb3 = Btl + (size_t)c * H1_ * K1;
  const f16* tbs[4] = {tb0, tb1, tb2, tb3};

  // 8 staging issues per thread: unit u = (q*4+w)*64 + lane covers all 2048 16B-units
  const f16* srcp[8];
#pragma unroll
  for (int q = 0; q < 8; ++q) {
    const int u = (q * 4 + w) * 64 + lane;
    const int tile = u >> 9, rem = u & 511;
    const int k8 = rem >> 7, row = rem & 127;
    const int rbase = (tile < 2) ? (m0 + row) : (n0 + row);
    srcp[q] = tbs[tile] + (size_t)rbase * K1 + k8 * 8;
  }

  f32x4 accm[4][4], accc[4][4];
#pragma unroll
  for (int i = 0; i < 4; ++i)
#pragma unroll
    for (int j = 0; j < 4; ++j) {
      accm[i][j] = (f32x4){0.f, 0.f, 0.f, 0.f};
      accc[i][j] = (f32x4){0.f, 0.f, 0.f, 0.f};
    }

  const int kg = lane >> 4;      // k-group 0..3
  const int lr = lane & 15;

#pragma unroll 1
  for (int kt = 0; kt < 8; ++kt) {
    __syncthreads();
#pragma unroll
    for (int q = 0; q < 8; ++q) {
      __builtin_amdgcn_global_load_lds(
          (const __attribute__((address_space(1))) void*)srcp[q],
          (__attribute__((address_space(3))) void*)((char*)&lds[0][0][0][0] + (q * 4 + w) * 1024),
          16, 0, 0);
      srcp[q] += 32;   // next K-chunk (64B)
    }
    __syncthreads();

    f16x8 ah[4], al[4];
#pragma unroll
    for (int i = 0; i < 4; ++i) {
      ah[i] = *(const f16x8*)&lds[0][kg][wr * 64 + i * 16 + lr][0];
      al[i] = *(const f16x8*)&lds[1][kg][wr * 64 + i * 16 + lr][0];
    }
#pragma unroll
    for (int j = 0; j < 4; ++j) {
      f16x8 bh = *(const f16x8*)&lds[2][kg][wc * 64 + j * 16 + lr][0];
      f16x8 bl = *(const f16x8*)&lds[3][kg][wc * 64 + j * 16 + lr][0];
#pragma unroll
      for (int i = 0; i < 4; ++i) {
        accm[i][j] = __builtin_amdgcn_mfma_f32_16x16x32_f16(ah[i], bh, accm[i][j], 0, 0, 0);
        accc[i][j] = __builtin_amdgcn_mfma_f32_16x16x32_f16(ah[i], bl, accc[i][j], 0, 0, 0);
        accc[i][j] = __builtin_amdgcn_mfma_f32_16x16x32_f16(al[i], bh, accc[i][j], 0, 0, 0);
      }
    }
  }

  // epilogue: v = accm + accc * 2^-11 ; spike >= 1.0 ; C/D: col=lane&15, row=(lane>>4)*4+r
  unsigned char* S = Sbase + (size_t)z * M1 * H1_;
#pragma unroll
  for (int i = 0; i < 4; ++i)
#pragma unroll
    for (int j = 0; j < 4; ++j) {
      const int n = n0 + wc * 64 + j * 16 + lr;
#pragma unroll
      for (int r = 0; r < 4; ++r) {
        const int m = m0 + wr * 64 + i * 16 + kg * 4 + r;
        float v = accm[i][j][r] + accc[i][j][r] * 4.8828125e-4f;
        S[(size_t)m * H1_ + n] = (v >= 1.0f) ? 1 : 0;
      }
    }
}

// ---------------------------------------------------------------- GEMM2 + spike
__global__ __launch_bounds__(256)
void gemm2_kernel(const unsigned char* __restrict__ Sbase,
                  const float* __restrict__ Wself2,
                  const float* __restrict__ Wnbr2,
                  unsigned char* __restrict__ outsbase)
{
  const int z = blockIdx.y;
  const int c = (z < 8) ? 0 : 1;
  const unsigned char* __restrict__ S = Sbase + (size_t)z * M1 * H1_;
  const float* __restrict__ Bw0 = Wself2 + (size_t)c * H1_ * H2_;
  const float* __restrict__ Bw1 = Wnbr2  + (size_t)c * H1_ * H2_;
  unsigned char* __restrict__ outs = outsbase + (size_t)z * B_ * H2_;
  const int m0 = blockIdx.x * 64;
  const int tid = threadIdx.x;

  __shared__ float As2[32][68];
  __shared__ float Bs2[32][68];

  const int arow = tid >> 2;
  const int acol = (tid & 3) << 3;
  const int brow = tid >> 4;
  const int bcol = (tid & 15) << 2;
  const int ty = tid >> 4;
  const int tx = tid & 15;

  float acc[4][4];
#pragma unroll
  for (int i = 0; i < 4; ++i)
#pragma unroll
    for (int j = 0; j < 4; ++j) acc[i][j] = 0.f;

#pragma unroll 1
  for (int kt = 0; kt < 32; ++kt) {
    const int k0 = kt * 32;
    float av[8];
    if (k0 < H1_) {
      const unsigned char* p = S + (size_t)(m0 + arow) * H1_ + k0 + acol;
      unsigned long long u = *(const unsigned long long*)p;
#pragma unroll
      for (int e = 0; e < 8; ++e) av[e] = (float)((u >> (8 * e)) & 0xFFull);
    } else {
      const int kk0 = k0 - H1_ + acol;
      unsigned int q[8] = {0, 0, 0, 0, 0, 0, 0, 0};
#pragma unroll
      for (int s = 0; s < S1_; ++s) {
        const unsigned char* p =
            S + ((size_t)B_ + (size_t)(m0 + arow) * S1_ + s) * H1_ + kk0;
        unsigned long long u = *(const unsigned long long*)p;
#pragma unroll
        for (int e = 0; e < 8; ++e) q[e] += (unsigned)((u >> (8 * e)) & 0xFFull);
      }
#pragma unroll
      for (int e = 0; e < 8; ++e) av[e] = (float)q[e] * 0.2f;
    }
    const int kg0 = k0 + brow, kg1 = kg0 + 16;
    const float* p0 = (kg0 < H1_) ? (Bw0 + (size_t)kg0 * H2_) : (Bw1 + (size_t)(kg0 - H1_) * H2_);
    const float* p1 = (kg1 < H1_) ? (Bw0 + (size_t)kg1 * H2_) : (Bw1 + (size_t)(kg1 - H1_) * H2_);
    float4 pb0 = *(const float4*)(p0 + bcol);
    float4 pb1 = *(const float4*)(p1 + bcol);

    __syncthreads();
#pragma unroll
    for (int e = 0; e < 8; ++e) As2[acol + e][arow] = av[e];
    *(float4*)&Bs2[brow][bcol]      = pb0;
    *(float4*)&Bs2[brow + 16][bcol] = pb1;
    __syncthreads();

#pragma unroll
    for (int kk = 0; kk < 32; ++kk) {
      float4 a4 = *(const float4*)&As2[kk][ty * 4];
      float4 b4 = *(const float4*)&Bs2[kk][tx * 4];
      float a[4] = {a4.x, a4.y, a4.z, a4.w};
      float b[4] = {b4.x, b4.y, b4.z, b4.w};
#pragma unroll
      for (int i = 0; i < 4; ++i)
#pragma unroll
        for (int j = 0; j < 4; ++j) acc[i][j] += a[i] * b[j];
    }
  }
#pragma unroll
  for (int i = 0; i < 4; ++i) {
    unsigned int pack = 0;
#pragma unroll
    for (int j = 0; j < 4; ++j)
      if (acc[i][j] >= 1.0f) pack |= (1u << (8 * j));
    *(unsigned int*)(outs + (size_t)(m0 + ty * 4 + i) * H2_ + tx * 4) = pack;
  }
}

// ---------------------------------------------------------------- attention + head
__global__ __launch_bounds__(256)
void final_kernel(const unsigned char* __restrict__ outsbase,
                  const float* __restrict__ postab,
                  const float* __restrict__ apw, const float* __restrict__ apb,
                  const float* __restrict__ anw, const float* __restrict__ anb,
                  const float* __restrict__ mtgw, const float* __restrict__ mtgb,
                  float* __restrict__ out)
{
  const int b = blockIdx.x * 4 + (threadIdx.x >> 6);
  const int lane = threadIdx.x & 63;
  float stacked = 0.f;
#pragma unroll
  for (int c = 0; c < 2; ++c) {
    const int Tc = c ? 4 : 8;
    const int zb = c ? 8 : 0;
    const float wp = apw[c * H2_ + lane];
    const float wn = anw[c * H2_ + lane];
    float seqv[8], sp[8], sn[8];
#pragma unroll
    for (int tt = 0; tt < Tc; ++tt) {
      const float sv = (float)outsbase[((size_t)(zb + tt) * B_ + b) * H2_ + lane];
      seqv[tt] = sv;
      sp[tt] = wsum64((sv + postab[tt * H2_ + lane]) * wp);
      sn[tt] = wsum64(sv * wn);
    }
    const float bp = apb[c], bn = anb[c];
    float mp = -3.4e38f, mn = -3.4e38f;
#pragma unroll
    for (int tt = 0; tt < Tc; ++tt) {
      sp[tt] += bp; sn[tt] += bn;
      mp = fmaxf(mp, sp[tt]); mn = fmaxf(mn, sn[tt]);
    }
    float ep[8], en[8], sump = 0.f, sumn = 0.f;
#pragma unroll
    for (int tt = 0; tt < Tc; ++tt) {
      ep[tt] = expf(sp[tt] - mp);
      en[tt] = expf(sn[tt] - mn);
      sump += ep[tt]; sumn += en[tt];
    }
    float embp = 0.f, embn = 0.f;
#pragma unroll
    for (int tt = 0; tt < Tc; ++tt) {
      embp += (seqv[tt] + postab[tt * H2_ + lane]) * (ep[tt] / sump);
      embn += seqv[tt] * (en[tt] / sumn);
    }
    stacked += 0.5f * (0.6f * embp + 0.4f * embn);
  }
  float res = 0.f;
#pragma unroll
  for (int o = 0; o < O_; ++o) {
    float r = wsum64(stacked * mtgw[lane * O_ + o]);
    if (lane == o) res = r;
  }
  if (lane < O_) out[(size_t)b * O_ + lane] = res + mtgb[lane];
}

// ---------------------------------------------------------------- launch
extern "C" void kernel_launch(void* const* d_in, const int* in_sizes, int n_in,
                              void* d_out, int out_size, void* d_ws, size_t ws_size,
                              hipStream_t stream)
{
  const int*   nodes  = (const int*)d_in[0];
  const int*   hop1   = (const int*)d_in[1];
  const int*   hop2   = (const int*)d_in[2];
  const float* x      = (const float*)d_in[3];
  const float* Wself1 = (const float*)d_in[4];
  const float* Wnbr1  = (const float*)d_in[5];
  const float* Wself2 = (const float*)d_in[6];
  const float* Wnbr2  = (const float*)d_in[7];
  const float* apw    = (const float*)d_in[8];
  const float* apb    = (const float*)d_in[9];
  const float* anw    = (const float*)d_in[10];
  const float* anb    = (const float*)d_in[11];
  const float* mtgw   = (const float*)d_in[12];
  const float* mtgb   = (const float*)d_in[13];
  float* out = (float*)d_out;

  char* ws = (char*)d_ws;
  size_t off = 0;
  float* postab = (float*)(ws + off);               off += 4096;
  f16* Ahb = (f16*)(ws + off);                      off += (size_t)T_ * M1 * K1 * 2;  // 100.7 MB
  f16* Alb = (f16*)(ws + off);                      off += (size_t)T_ * M1 * K1 * 2;  // 100.7 MB
  unsigned char* Sbase = (unsigned char*)(ws + off); off += (size_t)NZ * M1 * H1_;    // 151.0 MB
  unsigned char* outsb = (unsigned char*)(ws + off); off += (size_t)NZ * B_ * H2_;    //   3.1 MB
  if (ws_size < off) return;
  // B weight limbs live in the outs region during gemm1 (gemm2 overwrites later;
  // stream-ordered, so no aliasing hazard). 1.0 MB < 3.1 MB.
  f16* Bth = (f16*)outsb;
  f16* Btl = Bth + (size_t)2 * H1_ * K1;

  hipLaunchKernelGGL(postab_kernel, dim3(1), dim3(512), 0, stream, postab);
  hipLaunchKernelGGL(prep_w, dim3(1024), dim3(256), 0, stream, Wself1, Wnbr1, Bth, Btl);
  hipLaunchKernelGGL(gather_kernel, dim3(M1 / 4, T_), dim3(256), 0, stream,
                     nodes, hop1, hop2, x, Ahb, Alb);
  hipLaunchKernelGGL(gemm1_mfma, dim3(4, M1 / 128, NZ), dim3(256), 0, stream,
                     Ahb, Alb, Bth, Btl, Sbase);
  hipLaunchKernelGGL(gemm2_kernel, dim3(B_ / 64, NZ), dim3(256), 0, stream,
                     Sbase, Wself2, Wnbr2, outsb);
  hipLaunchKernelGGL(final_kernel, dim3(B_ / 4), dim3(256), 0, stream,
                     outsb, postab, apw, apb, anw, anb, mtgw, mtgb, out);
}

// Round 4
// 678.598 us; speedup vs baseline: 2.2474x; 1.3271x over previous
//
#include <hip/hip_runtime.h>
#include <math.h>

typedef _Float16 f16;
typedef _Float16 f16x8 __attribute__((ext_vector_type(8)));
typedef float f32x4 __attribute__((ext_vector_type(4)));

#define T_ 8
#define NNODES 100000
#define F_ 128
#define B_ 4096
#define S1_ 5
#define S2_ 2
#define H1_ 512
#define H2_ 64
#define O_ 32
#define M1 (B_ + B_*S1_)      /* 24576 rows: [h0-block | h1-block] */
#define K1 (2*F_)             /* 256: [h | agg] */
#define NZ 12                 /* z<8 -> (t=z,c=0); z>=8 -> (t=2*(z-8),c=1) */

__device__ __forceinline__ float wsum64(float v) {
#pragma unroll
  for (int o = 32; o > 0; o >>= 1) v += __shfl_xor(v, o, 64);
  return v;
}

// ---------------------------------------------------------------- pos table
__global__ __launch_bounds__(512) void postab_kernel(float* __restrict__ postab) {
  int i = threadIdx.x;
  int p = i >> 6, d = i & 63;
  double ang = (double)p / pow(10000.0, (2.0 * (double)(d >> 1)) / 64.0);
  postab[i] = (float)((d & 1) ? cos(ang) : sin(ang));
}

// ---------------------------------------------------------------- gemm1 weight limbs
// Bt[c][n=512][k=256] f16; k<128 from Wself1, k>=128 from Wnbr1 (transposed)
__global__ __launch_bounds__(256)
void prep_w(const float* __restrict__ Ws1, const float* __restrict__ Wn1,
            f16* __restrict__ Bth, f16* __restrict__ Btl) {
  const int bid = blockIdx.x;            // 0..1023
  const int c = bid >> 9, n = bid & 511;
  const int k = threadIdx.x;             // 0..255
  float wv = (k < F_) ? Ws1[((size_t)c * F_ + k) * H1_ + n]
                      : Wn1[((size_t)c * F_ + (k - F_)) * H1_ + n];
  f16 hi = (f16)wv;
  f16 lo = (f16)((wv - (float)hi) * 2048.0f);
  size_t o = ((size_t)c * H1_ + n) * K1 + k;
  Bth[o] = hi; Btl[o] = lo;
}

// ---------------------------------------------------------------- gemm2 weight limbs
// B2t[c][n=64][k=1024] f16; k<512: Ws2[k][n]; k>=512: 0.2f*Wn2[k-512][n]
__global__ __launch_bounds__(256)
void prep_w2(const float* __restrict__ Ws2, const float* __restrict__ Wn2,
             f16* __restrict__ B2h, f16* __restrict__ B2l) {
  const int c = blockIdx.x >> 6, n = blockIdx.x & 63;
#pragma unroll
  for (int q = 0; q < 4; ++q) {
    const int k = q * 256 + threadIdx.x;
    float v = (k < H1_) ? Ws2[((size_t)c * H1_ + k) * H2_ + n]
                        : 0.2f * Wn2[((size_t)c * H1_ + (k - H1_)) * H2_ + n];
    f16 hi = (f16)v;
    f16 lo = (f16)((v - (float)hi) * 2048.0f);
    size_t o = ((size_t)c * H2_ + n) * 1024 + k;
    B2h[o] = hi; B2l[o] = lo;
  }
}

// ---------------------------------------------------------------- gather+agg
__global__ __launch_bounds__(256) void gather_kernel(
    const int* __restrict__ nodes, const int* __restrict__ hop1,
    const int* __restrict__ hop2, const float* __restrict__ x,
    f16* __restrict__ Ah, f16* __restrict__ Al)
{
  const int t = blockIdx.y;
  const int r = blockIdx.x * 4 + (threadIdx.x >> 6);
  const int lane = threadIdx.x & 63;
  const int fo = (lane & 31) << 2;
  const bool hpart = lane < 32;
  const float* xt = x + (size_t)t * NNODES * F_;
  float4 v;
  if (r < B_) {
    if (hpart) {
      v = *(const float4*)(xt + (size_t)nodes[r] * F_ + fo);
    } else {
      v = make_float4(0.f, 0.f, 0.f, 0.f);
#pragma unroll
      for (int s = 0; s < S1_; ++s) {
        int idx = hop1[t * (B_ * S1_) + r * S1_ + s];
        float4 u = *(const float4*)(xt + (size_t)idx * F_ + fo);
        v.x += u.x; v.y += u.y; v.z += u.z; v.w += u.w;
      }
      v.x /= 5.0f; v.y /= 5.0f; v.z /= 5.0f; v.w /= 5.0f;
    }
  } else {
    const int j = r - B_;
    if (hpart) {
      v = *(const float4*)(xt + (size_t)hop1[t * (B_ * S1_) + j] * F_ + fo);
    } else {
      v = make_float4(0.f, 0.f, 0.f, 0.f);
#pragma unroll
      for (int s = 0; s < S2_; ++s) {
        int idx = hop2[t * (B_ * S1_ * S2_) + j * S2_ + s];
        float4 u = *(const float4*)(xt + (size_t)idx * F_ + fo);
        v.x += u.x; v.y += u.y; v.z += u.z; v.w += u.w;
      }
      v.x *= 0.5f; v.y *= 0.5f; v.z *= 0.5f; v.w *= 0.5f;
    }
  }
  union { f16 h[4]; uint2 u; } H, L;
  float vv[4] = {v.x, v.y, v.z, v.w};
#pragma unroll
  for (int e = 0; e < 4; ++e) {
    f16 hi = (f16)vv[e];
    H.h[e] = hi;
    L.h[e] = (f16)((vv[e] - (float)hi) * 2048.0f);
  }
  const size_t base = ((size_t)t * M1 + r) * K1 + 4 * lane;
  *(uint2*)(Ah + base) = H.u;
  *(uint2*)(Al + base) = L.u;
}

// ---------------------------------------------------------------- GEMM1 (MFMA fp16x3) + spike
// 2-phase double-buffered pipeline; XCD-swizzled block mapping.
__global__ __launch_bounds__(256)
void gemm1_mfma(const f16* __restrict__ Ah, const f16* __restrict__ Al,
                const f16* __restrict__ Bth, const f16* __restrict__ Btl,
                unsigned char* __restrict__ Sbase)
{
  // bijective XCD swizzle: 9216 blocks = 8 XCDs x 1152.
  const int hid = blockIdx.x + 4 * blockIdx.y + 768 * blockIdx.z;
  const int xcd = hid & 7, ii = hid >> 3;
  const int nblk = ii & 3;                  // N-block 0..3
  const int pair = xcd * 288 + (ii >> 2);   // 0..2303 = (yblk,z) pair
  const int yblk = pair % 192;
  const int z    = pair / 192;

  const int t = (z < 8) ? z : 2 * (z - 8);
  const int c = (z < 8) ? 0 : 1;
  const int m0 = yblk * 128;
  const int n0 = nblk * 128;
  const int tid = threadIdx.x;
  const int lane = tid & 63;
  const int w = tid >> 6;
  const int wr = w >> 1, wc = w & 1;

  __shared__ f16 lds[2][4][4][128][8];   // [buf][tile 0:Ah 1:Al 2:Bh 3:Bl][k8][row][8] = 64KB

  const f16* tb0 = Ah  + (size_t)t * M1 * K1;
  const f16* tb1 = Al  + (size_t)t * M1 * K1;
  const f16* tb2 = Bth + (size_t)c * H1_ * K1;
  const f16* tb3 = Btl + (size_t)c * H1_ * K1;
  const f16* tbs[4] = {tb0, tb1, tb2, tb3};

  const f16* srcp[8];
#pragma unroll
  for (int q = 0; q < 8; ++q) {
    const int u = (q * 4 + w) * 64 + lane;
    const int tile = u >> 9, rem = u & 511;
    const int k8 = rem >> 7, row = rem & 127;
    const int rbase = (tile < 2) ? (m0 + row) : (n0 + row);
    srcp[q] = tbs[tile] + (size_t)rbase * K1 + k8 * 8;
  }

  auto stage = [&](int buf) {
#pragma unroll
    for (int q = 0; q < 8; ++q) {
      __builtin_amdgcn_global_load_lds(
          (const __attribute__((address_space(1))) void*)srcp[q],
          (__attribute__((address_space(3))) void*)((char*)lds + buf * 32768 + (q * 4 + w) * 1024),
          16, 0, 0);
      srcp[q] += 32;
    }
  };

  f32x4 accm[4][4], accc[4][4];
#pragma unroll
  for (int i = 0; i < 4; ++i)
#pragma unroll
    for (int j = 0; j < 4; ++j) {
      accm[i][j] = (f32x4){0.f, 0.f, 0.f, 0.f};
      accc[i][j] = (f32x4){0.f, 0.f, 0.f, 0.f};
    }

  const int kg = lane >> 4;
  const int lr = lane & 15;

  stage(0);
  __syncthreads();   // buf0 ready (vmcnt drained before barrier)

#pragma unroll 1
  for (int kt = 0; kt < 8; ++kt) {
    const int cur = kt & 1;
    if (kt < 7) stage(cur ^ 1);   // prefetch next tile; hides under MFMA below

    f16x8 ah[4], al[4];
#pragma unroll
    for (int i = 0; i < 4; ++i) {
      ah[i] = *(const f16x8*)&lds[cur][0][kg][wr * 64 + i * 16 + lr][0];
      al[i] = *(const f16x8*)&lds[cur][1][kg][wr * 64 + i * 16 + lr][0];
    }
#pragma unroll
    for (int j = 0; j < 4; ++j) {
      f16x8 bh = *(const f16x8*)&lds[cur][2][kg][wc * 64 + j * 16 + lr][0];
      f16x8 bl = *(const f16x8*)&lds[cur][3][kg][wc * 64 + j * 16 + lr][0];
#pragma unroll
      for (int i = 0; i < 4; ++i) {
        accm[i][j] = __builtin_amdgcn_mfma_f32_16x16x32_f16(ah[i], bh, accm[i][j], 0, 0, 0);
        accc[i][j] = __builtin_amdgcn_mfma_f32_16x16x32_f16(ah[i], bl, accc[i][j], 0, 0, 0);
        accc[i][j] = __builtin_amdgcn_mfma_f32_16x16x32_f16(al[i], bh, accc[i][j], 0, 0, 0);
      }
    }
    __syncthreads();   // drains prefetch + protects buf reuse
  }

  unsigned char* S = Sbase + (size_t)z * M1 * H1_;
#pragma unroll
  for (int i = 0; i < 4; ++i)
#pragma unroll
    for (int j = 0; j < 4; ++j) {
      const int n = n0 + wc * 64 + j * 16 + lr;
#pragma unroll
      for (int r = 0; r < 4; ++r) {
        const int m = m0 + wr * 64 + i * 16 + kg * 4 + r;
        float v = accm[i][j][r] + accc[i][j][r] * 4.8828125e-4f;
        S[(size_t)m * H1_ + n] = (v >= 1.0f) ? 1 : 0;
      }
    }
}

// ---------------------------------------------------------------- A2 build (S -> f16 exact)
// A2[z][4096][1024]: k<512 = s0 bytes; k>=512 = q = sum_{s<5} s1 bytes (int 0..5)
__global__ __launch_bounds__(256)
void prep_a2(const unsigned char* __restrict__ Sbase, f16* __restrict__ A2)
{
  const int z = blockIdx.y;
  const int r = blockIdx.x * 4 + (threadIdx.x >> 6);
  const int lane = threadIdx.x & 63;
  const unsigned char* Sz = Sbase + (size_t)z * M1 * H1_;
  f16* A2row = A2 + ((size_t)z * B_ + r) * 1024;

  unsigned long long u = *(const unsigned long long*)(Sz + (size_t)r * H1_ + lane * 8);
  union { f16 h[8]; uint4 v; } P;
#pragma unroll
  for (int e = 0; e < 8; ++e) P.h[e] = (f16)(int)((u >> (8 * e)) & 0xFFull);
  *(uint4*)(A2row + lane * 8) = P.v;

  unsigned int q[8] = {0, 0, 0, 0, 0, 0, 0, 0};
#pragma unroll
  for (int s = 0; s < S1_; ++s) {
    unsigned long long us = *(const unsigned long long*)(
        Sz + ((size_t)B_ + (size_t)r * S1_ + s) * H1_ + lane * 8);
#pragma unroll
    for (int e = 0; e < 8; ++e) q[e] += (unsigned)((us >> (8 * e)) & 0xFFull);
  }
#pragma unroll
  for (int e = 0; e < 8; ++e) P.h[e] = (f16)(int)q[e];
  *(uint4*)(A2row + H1_ + lane * 8) = P.v;
}

// ---------------------------------------------------------------- GEMM2 (MFMA, exact-A 2-limb B) + spike
// M=4096 N=64 K=1024 per z. Block: 128x64, 4 waves (32x64 each), BK=32, dbuf.
__global__ __launch_bounds__(256)
void gemm2_mfma(const f16* __restrict__ A2,
                const f16* __restrict__ B2h, const f16* __restrict__ B2l,
                unsigned char* __restrict__ outsbase)
{
  const int z = blockIdx.y;
  const int c = (z < 8) ? 0 : 1;
  const int m0 = blockIdx.x * 128;
  const int tid = threadIdx.x;
  const int lane = tid & 63;
  const int wv = tid >> 6;

  __shared__ f16 lds2[2][8192];   // [buf][A:4096 | Bh:2048 | Bl:2048] f16 = 32 KB

  const f16* Az  = A2 + (size_t)z * B_ * 1024;
  const f16* Bhc = B2h + (size_t)c * H2_ * 1024;
  const f16* Blc = B2l + (size_t)c * H2_ * 1024;

  // staging: 1024 16B-units/step; unit u = q*256 + wv*64 + lane -> LDS byte u*16
  const f16* srcp[4];
#pragma unroll
  for (int q = 0; q < 4; ++q) {
    const int u = q * 256 + tid;
    if (u < 512) {
      const int k8 = u >> 7, row = u & 127;
      srcp[q] = Az + (size_t)(m0 + row) * 1024 + k8 * 8;
    } else if (u < 768) {
      const int v = u - 512, k8 = v >> 6, row = v & 63;
      srcp[q] = Bhc + (size_t)row * 1024 + k8 * 8;
    } else {
      const int v = u - 768, k8 = v >> 6, row = v & 63;
      srcp[q] = Blc + (size_t)row * 1024 + k8 * 8;
    }
  }

  auto stage = [&](int buf) {
#pragma unroll
    for (int q = 0; q < 4; ++q) {
      // wave-uniform LDS base: unit block (q*4+wv)*1024; HW adds lane*16
      __builtin_amdgcn_global_load_lds(
          (const __attribute__((address_space(1))) void*)srcp[q],
          (__attribute__((address_space(3))) void*)((char*)lds2 + buf * 16384 + (q * 4 + wv) * 1024),
          16, 0, 0);
      srcp[q] += 32;
    }
  };

  f32x4 acch[2][4], accl[2][4];
#pragma unroll
  for (int i = 0; i < 2; ++i)
#pragma unroll
    for (int j = 0; j < 4; ++j) {
      acch[i][j] = (f32x4){0.f, 0.f, 0.f, 0.f};
      accl[i][j] = (f32x4){0.f, 0.f, 0.f, 0.f};
    }

  const int kg = lane >> 4;
  const int lr = lane & 15;

  stage(0);
  __syncthreads();

#pragma unroll 1
  for (int kt = 0; kt < 32; ++kt) {
    const int cur = kt & 1;
    if (kt < 31) stage(cur ^ 1);

    f16x8 a[2];
#pragma unroll
    for (int i = 0; i < 2; ++i)
      a[i] = *(const f16x8*)&lds2[cur][(size_t)(kg * 128 + wv * 32 + i * 16 + lr) * 8];
#pragma unroll
    for (int j = 0; j < 4; ++j) {
      f16x8 bh = *(const f16x8*)&lds2[cur][4096 + (size_t)(kg * 64 + j * 16 + lr) * 8];
      f16x8 bl = *(const f16x8*)&lds2[cur][6144 + (size_t)(kg * 64 + j * 16 + lr) * 8];
#pragma unroll
      for (int i = 0; i < 2; ++i) {
        acch[i][j] = __builtin_amdgcn_mfma_f32_16x16x32_f16(a[i], bh, acch[i][j], 0, 0, 0);
        accl[i][j] = __builtin_amdgcn_mfma_f32_16x16x32_f16(a[i], bl, accl[i][j], 0, 0, 0);
      }
    }
    __syncthreads();
  }

  unsigned char* outs = outsbase + (size_t)z * B_ * H2_;
#pragma unroll
  for (int i = 0; i < 2; ++i)
#pragma unroll
    for (int j = 0; j < 4; ++j) {
      const int n = j * 16 + lr;
#pragma unroll
      for (int r = 0; r < 4; ++r) {
        const int m = m0 + wv * 32 + i * 16 + kg * 4 + r;
        float v = acch[i][j][r] + accl[i][j][r] * 4.8828125e-4f;
        outs[(size_t)m * H2_ + n] = (v >= 1.0f) ? 1 : 0;
      }
    }
}

// ---------------------------------------------------------------- attention + head
__global__ __launch_bounds__(256)
void final_kernel(const unsigned char* __restrict__ outsbase,
                  const float* __restrict__ postab,
                  const float* __restrict__ apw, const float* __restrict__ apb,
                  const float* __restrict__ anw, const float* __restrict__ anb,
                  const float* __restrict__ mtgw, const float* __restrict__ mtgb,
                  float* __restrict__ out)
{
  const int b = blockIdx.x * 4 + (threadIdx.x >> 6);
  const int lane = threadIdx.x & 63;
  float stacked = 0.f;
#pragma unroll
  for (int c = 0; c < 2; ++c) {
    const int Tc = c ? 4 : 8;
    const int zb = c ? 8 : 0;
    const float wp = apw[c * H2_ + lane];
    const float wn = anw[c * H2_ + lane];
    float seqv[8], sp[8], sn[8];
#pragma unroll
    for (int tt = 0; tt < Tc; ++tt) {
      const float sv = (float)outsbase[((size_t)(zb + tt) * B_ + b) * H2_ + lane];
      seqv[tt] = sv;
      sp[tt] = wsum64((sv + postab[tt * H2_ + lane]) * wp);
      sn[tt] = wsum64(sv * wn);
    }
    const float bp = apb[c], bn = anb[c];
    float mp = -3.4e38f, mn = -3.4e38f;
#pragma unroll
    for (int tt = 0; tt < Tc; ++tt) {
      sp[tt] += bp; sn[tt] += bn;
      mp = fmaxf(mp, sp[tt]); mn = fmaxf(mn, sn[tt]);
    }
    float ep[8], en[8], sump = 0.f, sumn = 0.f;
#pragma unroll
    for (int tt = 0; tt < Tc; ++tt) {
      ep[tt] = expf(sp[tt] - mp);
      en[tt] = expf(sn[tt] - mn);
      sump += ep[tt]; sumn += en[tt];
    }
    float embp = 0.f, embn = 0.f;
#pragma unroll
    for (int tt = 0; tt < Tc; ++tt) {
      embp += (seqv[tt] + postab[tt * H2_ + lane]) * (ep[tt] / sump);
      embn += seqv[tt] * (en[tt] / sumn);
    }
    stacked += 0.5f * (0.6f * embp + 0.4f * embn);
  }
  float res = 0.f;
#pragma unroll
  for (int o = 0; o < O_; ++o) {
    float r = wsum64(stacked * mtgw[lane * O_ + o]);
    if (lane == o) res = r;
  }
  if (lane < O_) out[(size_t)b * O_ + lane] = res + mtgb[lane];
}

// ---------------------------------------------------------------- launch
extern "C" void kernel_launch(void* const* d_in, const int* in_sizes, int n_in,
                              void* d_out, int out_size, void* d_ws, size_t ws_size,
                              hipStream_t stream)
{
  const int*   nodes  = (const int*)d_in[0];
  const int*   hop1   = (const int*)d_in[1];
  const int*   hop2   = (const int*)d_in[2];
  const float* x      = (const float*)d_in[3];
  const float* Wself1 = (const float*)d_in[4];
  const float* Wnbr1  = (const float*)d_in[5];
  const float* Wself2 = (const float*)d_in[6];
  const float* Wnbr2  = (const float*)d_in[7];
  const float* apw    = (const float*)d_in[8];
  const float* apb    = (const float*)d_in[9];
  const float* anw    = (const float*)d_in[10];
  const float* anb    = (const float*)d_in[11];
  const float* mtgw   = (const float*)d_in[12];
  const float* mtgb   = (const float*)d_in[13];
  float* out = (float*)d_out;

  char* ws = (char*)d_ws;
  size_t off = 0;
  float* postab = (float*)(ws + off);               off += 4096;
  f16* Ahb = (f16*)(ws + off);                      off += (size_t)T_ * M1 * K1 * 2;  // 100.66 MB
  f16* Alb = (f16*)(ws + off);                      off += (size_t)T_ * M1 * K1 * 2;  // 100.66 MB
  unsigned char* Sbase = (unsigned char*)(ws + off); off += (size_t)NZ * M1 * H1_;    // 151.0 MB
  unsigned char* outsb = (unsigned char*)(ws + off); off += (size_t)NZ * B_ * H2_;    //   3.1 MB
  if (ws_size < off) return;

  // stream-ordered aliases:
  //  - gemm1 B limbs live in outsb until gemm2 overwrites outs (1.0 MB < 3.1 MB)
  //  - A2 (12*4096*1024 f16) reuses Ahb after gemm1 (exact same size)
  //  - B2t limbs (512 KB) reuse Alb after gemm1
  f16* Bth = (f16*)outsb;
  f16* Btl = Bth + (size_t)2 * H1_ * K1;
  f16* A2  = Ahb;
  f16* B2h = Alb;
  f16* B2l = B2h + (size_t)2 * H2_ * 1024;

  hipLaunchKernelGGL(postab_kernel, dim3(1), dim3(512), 0, stream, postab);
  hipLaunchKernelGGL(prep_w, dim3(1024), dim3(256), 0, stream, Wself1, Wnbr1, Bth, Btl);
  hipLaunchKernelGGL(gather_kernel, dim3(M1 / 4, T_), dim3(256), 0, stream,
                     nodes, hop1, hop2, x, Ahb, Alb);
  hipLaunchKernelGGL(gemm1_mfma, dim3(4, M1 / 128, NZ), dim3(256), 0, stream,
                     Ahb, Alb, Bth, Btl, Sbase);
  hipLaunchKernelGGL(prep_w2, dim3(128), dim3(256), 0, stream, Wself2, Wnbr2, B2h, B2l);
  hipLaunchKernelGGL(prep_a2, dim3(B_ / 4, NZ), dim3(256), 0, stream, Sbase, A2);
  hipLaunchKernelGGL(gemm2_mfma, dim3(B_ / 128, NZ), dim3(256), 0, stream,
                     A2, B2h, B2l, outsb);
  hipLaunchKernelGGL(final_kernel, dim3(B_ / 4), dim3(256), 0, stream,
                     outsb, postab, apw, apb, anw, anb, mtgw, mtgb, out);
}